// Round 10
// baseline (323.807 us; speedup 1.0000x reference)
//
#include <hip/hip_runtime.h>

#define BB 64
#define SS 2048
#define FF 256
#define CC 32

typedef unsigned u32x2 __attribute__((ext_vector_type(2)));

// Two-result permlane swaps (builtin returns {vdst, vsrc} in distinct regs).
__device__ __forceinline__ void plswap16(int a_in, int& x, int& y) {
#if __has_builtin(__builtin_amdgcn_permlane16_swap)
    u32x2 r = __builtin_amdgcn_permlane16_swap((unsigned)a_in, (unsigned)a_in, false, false);
    x = (int)r[0]; y = (int)r[1];
#else
    int xx = a_in, yy;
    asm volatile("v_mov_b32 %0, %1" : "=v"(yy) : "v"(a_in));
    asm volatile("v_permlane16_swap_b32 %0, %1" : "+v"(xx), "+v"(yy));
    x = xx; y = yy;
#endif
}
__device__ __forceinline__ void plswap32(int a_in, int& x, int& y) {
#if __has_builtin(__builtin_amdgcn_permlane32_swap)
    u32x2 r = __builtin_amdgcn_permlane32_swap((unsigned)a_in, (unsigned)a_in, false, false);
    x = (int)r[0]; y = (int)r[1];
#else
    int xx = a_in, yy;
    asm volatile("v_mov_b32 %0, %1" : "=v"(yy) : "v"(a_in));
    asm volatile("v_permlane32_swap_b32 %0, %1" : "+v"(xx), "+v"(yy));
    x = xx; y = yy;
#endif
}

#if __has_builtin(__builtin_amdgcn_mov_dpp)
#define ROT1(d, s, K) d = __builtin_amdgcn_mov_dpp(s, 0x120 + K, 0xF, 0xF, false)
#else
#define ROT1(d, s, K) d = __builtin_amdgcn_update_dpp(s, s, 0x120 + K, 0xF, 0xF, false)
#endif
#define ROTALL(arr, s) \
    arr[0] = s;        \
    ROT1(arr[1], s, 1);  ROT1(arr[2], s, 2);  ROT1(arr[3], s, 3);  \
    ROT1(arr[4], s, 4);  ROT1(arr[5], s, 5);  ROT1(arr[6], s, 6);  \
    ROT1(arr[7], s, 7);  ROT1(arr[8], s, 8);  ROT1(arr[9], s, 9);  \
    ROT1(arr[10], s, 10); ROT1(arr[11], s, 11); ROT1(arr[12], s, 12); \
    ROT1(arr[13], s, 13); ROT1(arr[14], s, 14); ROT1(arr[15], s, 15)

__device__ __forceinline__ float fmax3_(float a, float b, float c) { return fmaxf(fmaxf(a, b), c); }

// ---------------------------------------------------------------------------
// Kernel 1: emissions GEMM — UNCHANGED (bit-exact; ~45 us).
// ---------------------------------------------------------------------------
__global__ __launch_bounds__(256) void emis_kernel(const float* __restrict__ X,
                                                   const float* __restrict__ W,
                                                   const float* __restrict__ bias,
                                                   float* __restrict__ em) {
    __shared__ __align__(16) float xs[64 * 260];
    __shared__ __align__(16) float wsh[32 * 260];
    const int tid = threadIdx.x;
    const long rowbase = (long)blockIdx.x * 64;

    const float4* Xg = (const float4*)(X + rowbase * FF);
#pragma unroll
    for (int i = 0; i < 16; ++i) {
        int idx = tid + i * 256;
        int r = idx >> 6, c4 = idx & 63;
        *(float4*)&xs[r * 260 + c4 * 4] = Xg[idx];
    }
    const float4* Wg = (const float4*)W;
#pragma unroll
    for (int i = 0; i < 8; ++i) {
        int idx = tid + i * 256;
        int r = idx >> 6, c4 = idx & 63;
        *(float4*)&wsh[r * 260 + c4 * 4] = Wg[idx];
    }
    __syncthreads();

    const int rp = tid >> 3;
    const int cg = (tid & 7) * 4;
    const int r0 = rp * 2, r1 = rp * 2 + 1;
    float acc0[4] = {0.f, 0.f, 0.f, 0.f};
    float acc1[4] = {0.f, 0.f, 0.f, 0.f};

#pragma unroll 4
    for (int k = 0; k < 256; k += 4) {
        float4 xa = *(const float4*)&xs[r0 * 260 + k];
        float4 xb = *(const float4*)&xs[r1 * 260 + k];
#pragma unroll
        for (int jj = 0; jj < 4; ++jj) {
            float4 w = *(const float4*)&wsh[(cg + jj) * 260 + k];
            acc0[jj] = fmaf(xa.x, w.x, acc0[jj]);
            acc0[jj] = fmaf(xa.y, w.y, acc0[jj]);
            acc0[jj] = fmaf(xa.z, w.z, acc0[jj]);
            acc0[jj] = fmaf(xa.w, w.w, acc0[jj]);
            acc1[jj] = fmaf(xb.x, w.x, acc1[jj]);
            acc1[jj] = fmaf(xb.y, w.y, acc1[jj]);
            acc1[jj] = fmaf(xb.z, w.z, acc1[jj]);
            acc1[jj] = fmaf(xb.w, w.w, acc1[jj]);
        }
    }
#pragma unroll
    for (int jj = 0; jj < 4; ++jj) {
        float bj = bias[cg + jj];
        em[(rowbase + r0) * CC + cg + jj] = acc0[jj] + bj;
        em[(rowbase + r1) * CC + cg + jj] = acc1[jj] + bj;
    }
}

// ---------------------------------------------------------------------------
// STEP2: r9 asm step with trimmed tail (mov+swap32+max; {own,partner} under
// commutative exact fmax -> bit-identical to r9's cndmask version).
// ---------------------------------------------------------------------------
#define STEP2_ASM(avar, evar)                                                       \
    do {                                                                            \
        float x_, b_, q0_, q1_, q2_, q3_, q4_, q5_, q6_, q7_,                       \
              q8_, q9_, q10_, q11_, q12_, q13_, q14_, q15_;                         \
        asm volatile(                                                               \
            "v_mov_b32 %[x], %[aa]\n\t"                                             \
            "s_nop 1\n\t"                                                           \
            "v_permlane16_swap_b32 %[x], %[aa]\n\t"                                 \
            "s_nop 0\n\t"                                                           \
            "v_cndmask_b32 %[bb], %[aa], %[x], %[m16]\n\t"                          \
            "s_nop 1\n\t"                                                           \
            "v_add_f32 %[q0], %[bb], %[t0]\n\t"                                     \
            "v_add_f32_dpp %[q1], %[bb], %[t1] row_ror:1 row_mask:0xf bank_mask:0xf\n\t"  \
            "v_add_f32_dpp %[q2], %[bb], %[t2] row_ror:2 row_mask:0xf bank_mask:0xf\n\t"  \
            "v_add_f32_dpp %[q3], %[bb], %[t3] row_ror:3 row_mask:0xf bank_mask:0xf\n\t"  \
            "v_add_f32_dpp %[q4], %[bb], %[t4] row_ror:4 row_mask:0xf bank_mask:0xf\n\t"  \
            "v_add_f32_dpp %[q5], %[bb], %[t5] row_ror:5 row_mask:0xf bank_mask:0xf\n\t"  \
            "v_add_f32_dpp %[q6], %[bb], %[t6] row_ror:6 row_mask:0xf bank_mask:0xf\n\t"  \
            "v_add_f32_dpp %[q7], %[bb], %[t7] row_ror:7 row_mask:0xf bank_mask:0xf\n\t"  \
            "v_add_f32_dpp %[q8], %[bb], %[t8] row_ror:8 row_mask:0xf bank_mask:0xf\n\t"  \
            "v_add_f32_dpp %[q9], %[bb], %[t9] row_ror:9 row_mask:0xf bank_mask:0xf\n\t"  \
            "v_add_f32_dpp %[q10], %[bb], %[t10] row_ror:10 row_mask:0xf bank_mask:0xf\n\t" \
            "v_add_f32_dpp %[q11], %[bb], %[t11] row_ror:11 row_mask:0xf bank_mask:0xf\n\t" \
            "v_add_f32_dpp %[q12], %[bb], %[t12] row_ror:12 row_mask:0xf bank_mask:0xf\n\t" \
            "v_add_f32_dpp %[q13], %[bb], %[t13] row_ror:13 row_mask:0xf bank_mask:0xf\n\t" \
            "v_add_f32_dpp %[q14], %[bb], %[t14] row_ror:14 row_mask:0xf bank_mask:0xf\n\t" \
            "v_add_f32_dpp %[q15], %[bb], %[t15] row_ror:15 row_mask:0xf bank_mask:0xf\n\t" \
            "v_max3_f32 %[q0], %[q0], %[q1], %[q2]\n\t"                             \
            "v_max3_f32 %[q3], %[q3], %[q4], %[q5]\n\t"                             \
            "v_max3_f32 %[q6], %[q6], %[q7], %[q8]\n\t"                             \
            "v_max3_f32 %[q9], %[q9], %[q10], %[q11]\n\t"                           \
            "v_max3_f32 %[q12], %[q12], %[q13], %[q14]\n\t"                         \
            "v_max3_f32 %[q0], %[q0], %[q3], %[q6]\n\t"                             \
            "v_max3_f32 %[q9], %[q9], %[q12], %[q15]\n\t"                           \
            "v_max_f32 %[q0], %[q0], %[q9]\n\t"                                     \
            "v_mov_b32 %[x], %[q0]\n\t"                                             \
            "s_nop 1\n\t"                                                           \
            "v_permlane32_swap_b32 %[x], %[q0]\n\t"                                 \
            "s_nop 0\n\t"                                                           \
            "v_max_f32 %[q0], %[q0], %[x]\n\t"                                      \
            "v_add_f32 %[aa], %[q0], %[ee]\n\t"                                     \
            : [aa] "+v"(avar), [x] "=&v"(x_), [bb] "=&v"(b_),                       \
              [q0] "=&v"(q0_), [q1] "=&v"(q1_), [q2] "=&v"(q2_), [q3] "=&v"(q3_),   \
              [q4] "=&v"(q4_), [q5] "=&v"(q5_), [q6] "=&v"(q6_), [q7] "=&v"(q7_),   \
              [q8] "=&v"(q8_), [q9] "=&v"(q9_), [q10] "=&v"(q10_),                  \
              [q11] "=&v"(q11_), [q12] "=&v"(q12_), [q13] "=&v"(q13_),              \
              [q14] "=&v"(q14_), [q15] "=&v"(q15_)                                  \
            : [ee] "v"(evar), [t0] "v"(Ti[0]), [t1] "v"(Ti[1]), [t2] "v"(Ti[2]),    \
              [t3] "v"(Ti[3]), [t4] "v"(Ti[4]), [t5] "v"(Ti[5]), [t6] "v"(Ti[6]),   \
              [t7] "v"(Ti[7]), [t8] "v"(Ti[8]), [t9] "v"(Ti[9]), [t10] "v"(Ti[10]), \
              [t11] "v"(Ti[11]), [t12] "v"(Ti[12]), [t13] "v"(Ti[13]),              \
              [t14] "v"(Ti[14]), [t15] "v"(Ti[15]),                                 \
              [m16] "s"(mask16));                                                   \
    } while (0)

// ---------------------------------------------------------------------------
// Kernel 2 (FUSED): 64 blocks x 256 threads (1 block/CU, 4 waves on 4 SIMDs).
//   Wave 0  = producer: serial alpha chain, writes alpha to LDS ring (8 slots
//             x 64 steps x 32 states), publishes per-chunk progress flag.
//   Waves 1-3 = consumers: per 64-step chunk (round-robin mod 3), recompute bp
//             from LDS alphas (exact r6 math), store bp + chunk-LUT G.
//   Consumer load (~70us/wave) hides fully under producer (~190us).
// ---------------------------------------------------------------------------
__global__ __launch_bounds__(256, 1) void viterbi_fused(const float* __restrict__ em,
                                                        const float* __restrict__ T,
                                                        const float* __restrict__ startT,
                                                        const float* __restrict__ endT,
                                                        unsigned* __restrict__ bp,
                                                        unsigned char* __restrict__ G,
                                                        float* __restrict__ out) {
    __shared__ float aring[8 * 2048];      // 64 KB alpha ring, slot = chunk & 7
    __shared__ int prog;                   // chunks completed by producer

    const int tid = threadIdx.x;
    const int w = tid >> 6;
    const int l = tid & 63;
    const int b = blockIdx.x;
    const int j = l & 31;
    const int h = l >> 5;

    if (tid == 0) prog = 0;
    __syncthreads();

    // common probes (both roles use the same maps)
    int p0, p1;
    plswap16(j, p0, p1);
    const bool c16 = (((p0 >> 4) & 1) == h);
    const int pm = c16 ? p0 : p1;
    int mk[16];
    ROTALL(mk, pm);
    int q0p, q1p;
    plswap32(l, q0p, q1p);
    const bool pick0 = (q0p == (l ^ 32));

    float Ti[16];
#pragma unroll
    for (int k = 0; k < 16; ++k) Ti[k] = T[mk[k] * CC + j];

    if (w == 0) {
        // ------------------------- producer -------------------------
        const unsigned long long mask16 = __ballot(c16);
        const float* eb = em + (long)b * SS * CC;

        float eq[8];
#pragma unroll
        for (int v = 0; v < 8; ++v) eq[v] = eb[v * 32 + j];

        float a = startT[j] + eq[0];       // alpha_0
        aring[j] = a;                      // slot 0, u = 0
        eq[0] = eb[8 * 32 + j];

        auto flagset = [&](int v) {
            asm volatile("s_waitcnt lgkmcnt(0)" ::: "memory");
            if (l == 0) *(volatile int*)&prog = v;
        };

        // chunk 0: u = 1..63  (t = u)
#pragma unroll
        for (int uu = 1; uu < 8; ++uu) {
            STEP2_ASM(a, eq[uu]);
            aring[uu * 32 + j] = a;
            eq[uu] = eb[(uu + 8) * 32 + j];
        }
        for (int u8 = 1; u8 < 8; ++u8) {
#pragma unroll
            for (int uu = 0; uu < 8; ++uu) {
                int u = u8 * 8 + uu;
                STEP2_ASM(a, eq[uu]);
                aring[u * 32 + j] = a;
                eq[uu] = eb[(u + 8) * 32 + j];
            }
        }
        flagset(1);

        // chunks 1..30
        for (int c = 1; c < 31; ++c) {
            const int tb = c << 6;
            float* slot = &aring[(c & 7) * 2048];
            for (int u8 = 0; u8 < 8; ++u8) {
#pragma unroll
                for (int uu = 0; uu < 8; ++uu) {
                    int u = u8 * 8 + uu;
                    STEP2_ASM(a, eq[uu]);
                    slot[u * 32 + j] = a;
                    eq[uu] = eb[(tb + u + 8) * 32 + j];
                }
            }
            flagset(c + 1);
        }

        // chunk 31: t = 1984+u; refill only while t+8 <= 2047 (u <= 55)
        {
            float* slot = &aring[(31 & 7) * 2048];
            for (int u8 = 0; u8 < 7; ++u8) {
#pragma unroll
                for (int uu = 0; uu < 8; ++uu) {
                    int u = u8 * 8 + uu;
                    STEP2_ASM(a, eq[uu]);
                    slot[u * 32 + j] = a;
                    eq[uu] = eb[(1984 + u + 8) * 32 + j];
                }
            }
#pragma unroll
            for (int uu = 0; uu < 8; ++uu) {
                int u = 56 + uu;
                STEP2_ASM(a, eq[uu]);
                slot[u * 32 + j] = a;
            }
            flagset(32);
        }

        // final: best_score + last tag (tie -> lowest j)
        float v = a + endT[j];
        int idx = j;
#pragma unroll
        for (int d = 1; d <= 16; d <<= 1) {
            float ovv = __shfl_xor(v, d);
            int   oii = __shfl_xor(idx, d);
            bool c = (ovv > v) || (ovv == v && oii < idx);
            v = c ? ovv : v;
            idx = c ? oii : idx;
        }
        if (l == 0) {
            out[b] = v;
            out[BB + (long)b * SS + (SS - 1)] = (float)idx;
        }
    } else {
        // ------------------------- consumers -------------------------
        unsigned Bk[16];
#pragma unroll
        for (int kk = 0; kk < 16; ++kk) Bk[kk] = 1u << mk[kk];

        for (int c = w - 1; c < 32; c += 3) {
            while (*(volatile int*)&prog < c + 1) __builtin_amdgcn_s_sleep(2);
            asm volatile("" ::: "memory");
            const float* AS = &aring[(c & 7) * 2048];

            float aq[8];
#pragma unroll
            for (int v = 0; v < 8; ++v) aq[v] = AS[v * 32 + j];

            unsigned sr[16];
#pragma unroll
            for (int p = 0; p < 16; ++p) sr[p] = 0u;

#pragma unroll
            for (int g8 = 0; g8 < 8; ++g8) {
#pragma unroll
                for (int v = 0; v < 8; ++v) {
                    const int u = g8 * 8 + v;
                    float av = aq[v];
                    if (g8 < 7) aq[v] = AS[((g8 + 1) * 8 + v) * 32 + j];

                    int x, y;
                    plswap16(__float_as_int(av), x, y);
                    int base = c16 ? x : y;
                    int rot[16];
                    ROTALL(rot, base);
                    float s[16];
#pragma unroll
                    for (int kk = 0; kk < 16; ++kk) s[kk] = __int_as_float(rot[kk]) + Ti[kk];

                    float m0 = fmax3_(s[0], s[1], s[2]);
                    float m1 = fmax3_(s[3], s[4], s[5]);
                    float m2 = fmax3_(s[6], s[7], s[8]);
                    float m3 = fmax3_(s[9], s[10], s[11]);
                    float m4 = fmax3_(s[12], s[13], s[14]);
                    float mv = fmaxf(fmax3_(m0, m1, m2), fmax3_(m3, m4, s[15]));

                    int xm, ym;
                    plswap32(__float_as_int(mv), xm, ym);
                    float ov = __int_as_float(pick0 ? xm : ym);
                    float gv = fmaxf(mv, ov);

                    unsigned c0 = (s[0] == gv) ? Bk[0] : 0u,   c1 = (s[1] == gv) ? Bk[1] : 0u;
                    unsigned c2 = (s[2] == gv) ? Bk[2] : 0u,   c3 = (s[3] == gv) ? Bk[3] : 0u;
                    unsigned c4 = (s[4] == gv) ? Bk[4] : 0u,   c5 = (s[5] == gv) ? Bk[5] : 0u;
                    unsigned c6 = (s[6] == gv) ? Bk[6] : 0u,   c7 = (s[7] == gv) ? Bk[7] : 0u;
                    unsigned c8 = (s[8] == gv) ? Bk[8] : 0u,   c9 = (s[9] == gv) ? Bk[9] : 0u;
                    unsigned c10 = (s[10] == gv) ? Bk[10] : 0u, c11 = (s[11] == gv) ? Bk[11] : 0u;
                    unsigned c12 = (s[12] == gv) ? Bk[12] : 0u, c13 = (s[13] == gv) ? Bk[13] : 0u;
                    unsigned c14 = (s[14] == gv) ? Bk[14] : 0u, c15 = (s[15] == gv) ? Bk[15] : 0u;
                    unsigned msk = ((c0 | c1 | c2) | (c3 | c4 | c5)) |
                                   ((c6 | c7 | c8) | (c9 | c10 | c11)) |
                                   ((c12 | c13 | c14) | c15);

                    int xk, yk;
                    plswap32((int)msk, xk, yk);
                    unsigned om = (unsigned)(pick0 ? xk : yk);
                    int wi = __builtin_ctz(msk | om);

                    if (u == 63 && c == 31) wi = j;   // bp slot 2047 = identity
                    sr[u >> 2] |= (unsigned)wi << ((u & 3) * 8);
                }
            }

#pragma unroll
            for (int p = 0; p < 16; ++p)
                bp[((unsigned)(16 * c + p) * BB + b) * CC + j] = sr[p];

            int g = j;
#pragma unroll
            for (int rel = 63; rel >= 0; --rel) {
                unsigned dw = (unsigned)__builtin_amdgcn_ds_bpermute((g | (l & 32)) << 2,
                                                                     (int)sr[rel >> 2]);
                g = (int)((dw >> ((rel & 3) * 8)) & 31u);
            }
            G[(b * 32 + c) * 32 + j] = (unsigned char)g;
        }
    }
}

// ---------------------------------------------------------------------------
// bt_scan / bt_emit — r5/r6 proven versions (tagB removes the serial G-walk).
// ---------------------------------------------------------------------------
__global__ __launch_bounds__(64) void bt_scan(const unsigned char* __restrict__ G,
                                              const float* __restrict__ out,
                                              int* __restrict__ tagB) {
    __shared__ unsigned char Gs[64 * 32 * 32];
    const int l = threadIdx.x;
    const float4* Gg = (const float4*)G;
    float4* Gls = (float4*)Gs;
#pragma unroll
    for (int i = 0; i < 64; ++i) Gls[l + i * 64] = Gg[l + i * 64];
    __syncthreads();

    const int b = l;
    int cur = (int)out[BB + (long)b * SS + (SS - 1)];
    for (int k = 31; k >= 0; --k) {
        cur = Gs[(b * 32 + k) * 32 + cur];
        tagB[b * 32 + k] = cur;
    }
}

__global__ __launch_bounds__(64) void bt_emit(const unsigned* __restrict__ bp,
                                              const int* __restrict__ tagB,
                                              float* __restrict__ out) {
    const int l = threadIdx.x;
    const int b = blockIdx.x >> 5;
    const int k = blockIdx.x & 31;

    unsigned sr[16];
#pragma unroll
    for (int p = 0; p < 16; ++p) sr[p] = bp[((unsigned)(16 * k + p) * BB + b) * CC + (l & 31)];

    int start = (k == 31) ? (int)out[BB + (long)b * SS + (SS - 1)]
                          : tagB[b * 32 + k + 1];
    int g = start, cap = start;
#pragma unroll
    for (int rel = 63; rel >= 0; --rel) {
        unsigned dw = (unsigned)__builtin_amdgcn_ds_bpermute((g | (l & 32)) << 2,
                                                             (int)sr[rel >> 2]);
        g = (int)((dw >> ((rel & 3) * 8)) & 31u);
        cap = (l == rel) ? g : cap;
    }
    out[BB + (long)b * SS + k * 64 + l] = (float)cap;
}

// ---------------------------------------------------------------------------
extern "C" void kernel_launch(void* const* d_in, const int* in_sizes, int n_in,
                              void* d_out, int out_size, void* d_ws, size_t ws_size,
                              hipStream_t stream) {
    const float* X      = (const float*)d_in[0];
    const float* W      = (const float*)d_in[1];
    const float* bias   = (const float*)d_in[2];
    const float* T      = (const float*)d_in[3];
    const float* startT = (const float*)d_in[4];
    const float* endT   = (const float*)d_in[5];
    float* out = (float*)d_out;

    float*    em = (float*)d_ws;                                        // 16 MB (read-only after emis)
    unsigned* bp = (unsigned*)((char*)d_ws + (size_t)BB * SS * CC * 4); // 4 MB @ 16 MB
    unsigned char* G    = (unsigned char*)d_ws + (20u << 20);           // 64 KB @ 20 MB
    int*           tagB = (int*)((char*)d_ws + (20u << 20) + 65536);    // 8 KB

    emis_kernel<<<(BB * SS) / 64, 256, 0, stream>>>(X, W, bias, em);
    viterbi_fused<<<BB, 256, 0, stream>>>(em, T, startT, endT, bp, G, out);
    bt_scan<<<1, 64, 0, stream>>>(G, out, tagB);
    bt_emit<<<BB * 32, 64, 0, stream>>>(bp, tagB, out);
}

// Round 11
// 291.099 us; speedup vs baseline: 1.1124x; 1.1124x over previous
//
#include <hip/hip_runtime.h>

#define BB 64
#define SS 2048
#define FF 256
#define CC 32
#define CH 64   // chunks per sequence (32 steps each)

typedef unsigned u32x2 __attribute__((ext_vector_type(2)));

// Two-result permlane swaps (builtin returns {vdst, vsrc} in distinct regs).
__device__ __forceinline__ void plswap16(int a_in, int& x, int& y) {
#if __has_builtin(__builtin_amdgcn_permlane16_swap)
    u32x2 r = __builtin_amdgcn_permlane16_swap((unsigned)a_in, (unsigned)a_in, false, false);
    x = (int)r[0]; y = (int)r[1];
#else
    int xx = a_in, yy;
    asm volatile("v_mov_b32 %0, %1" : "=v"(yy) : "v"(a_in));
    asm volatile("v_permlane16_swap_b32 %0, %1" : "+v"(xx), "+v"(yy));
    x = xx; y = yy;
#endif
}
__device__ __forceinline__ void plswap32(int a_in, int& x, int& y) {
#if __has_builtin(__builtin_amdgcn_permlane32_swap)
    u32x2 r = __builtin_amdgcn_permlane32_swap((unsigned)a_in, (unsigned)a_in, false, false);
    x = (int)r[0]; y = (int)r[1];
#else
    int xx = a_in, yy;
    asm volatile("v_mov_b32 %0, %1" : "=v"(yy) : "v"(a_in));
    asm volatile("v_permlane32_swap_b32 %0, %1" : "+v"(xx), "+v"(yy));
    x = xx; y = yy;
#endif
}

#if __has_builtin(__builtin_amdgcn_mov_dpp)
#define ROT1(d, s, K) d = __builtin_amdgcn_mov_dpp(s, 0x120 + K, 0xF, 0xF, false)
#else
#define ROT1(d, s, K) d = __builtin_amdgcn_update_dpp(s, s, 0x120 + K, 0xF, 0xF, false)
#endif
#define ROTALL(arr, s) \
    arr[0] = s;        \
    ROT1(arr[1], s, 1);  ROT1(arr[2], s, 2);  ROT1(arr[3], s, 3);  \
    ROT1(arr[4], s, 4);  ROT1(arr[5], s, 5);  ROT1(arr[6], s, 6);  \
    ROT1(arr[7], s, 7);  ROT1(arr[8], s, 8);  ROT1(arr[9], s, 9);  \
    ROT1(arr[10], s, 10); ROT1(arr[11], s, 11); ROT1(arr[12], s, 12); \
    ROT1(arr[13], s, 13); ROT1(arr[14], s, 14); ROT1(arr[15], s, 15)

__device__ __forceinline__ float fmax3_(float a, float b, float c) { return fmaxf(fmaxf(a, b), c); }

// ---------------------------------------------------------------------------
// Kernel 1: emissions GEMM — r9 structure + float4 stores.
// ---------------------------------------------------------------------------
__global__ __launch_bounds__(256) void emis_kernel(const float* __restrict__ X,
                                                   const float* __restrict__ W,
                                                   const float* __restrict__ bias,
                                                   float* __restrict__ em) {
    __shared__ __align__(16) float xs[64 * 260];
    __shared__ __align__(16) float wsh[32 * 260];
    const int tid = threadIdx.x;
    const long rowbase = (long)blockIdx.x * 64;

    const float4* Xg = (const float4*)(X + rowbase * FF);
#pragma unroll
    for (int i = 0; i < 16; ++i) {
        int idx = tid + i * 256;
        int r = idx >> 6, c4 = idx & 63;
        *(float4*)&xs[r * 260 + c4 * 4] = Xg[idx];
    }
    const float4* Wg = (const float4*)W;
#pragma unroll
    for (int i = 0; i < 8; ++i) {
        int idx = tid + i * 256;
        int r = idx >> 6, c4 = idx & 63;
        *(float4*)&wsh[r * 260 + c4 * 4] = Wg[idx];
    }
    __syncthreads();

    const int rp = tid >> 3;
    const int cg = (tid & 7) * 4;
    const int r0 = rp * 2, r1 = rp * 2 + 1;
    float acc0[4] = {0.f, 0.f, 0.f, 0.f};
    float acc1[4] = {0.f, 0.f, 0.f, 0.f};

#pragma unroll 4
    for (int k = 0; k < 256; k += 4) {
        float4 xa = *(const float4*)&xs[r0 * 260 + k];
        float4 xb = *(const float4*)&xs[r1 * 260 + k];
#pragma unroll
        for (int jj = 0; jj < 4; ++jj) {
            float4 w = *(const float4*)&wsh[(cg + jj) * 260 + k];
            acc0[jj] = fmaf(xa.x, w.x, acc0[jj]);
            acc0[jj] = fmaf(xa.y, w.y, acc0[jj]);
            acc0[jj] = fmaf(xa.z, w.z, acc0[jj]);
            acc0[jj] = fmaf(xa.w, w.w, acc0[jj]);
            acc1[jj] = fmaf(xb.x, w.x, acc1[jj]);
            acc1[jj] = fmaf(xb.y, w.y, acc1[jj]);
            acc1[jj] = fmaf(xb.z, w.z, acc1[jj]);
            acc1[jj] = fmaf(xb.w, w.w, acc1[jj]);
        }
    }
    float4 b4 = *(const float4*)&bias[cg];
    float4 o0 = make_float4(acc0[0] + b4.x, acc0[1] + b4.y, acc0[2] + b4.z, acc0[3] + b4.w);
    float4 o1 = make_float4(acc1[0] + b4.x, acc1[1] + b4.y, acc1[2] + b4.z, acc1[3] + b4.w);
    *(float4*)&em[(rowbase + r0) * CC + cg] = o0;
    *(float4*)&em[(rowbase + r1) * CC + cg] = o1;
}

// ---------------------------------------------------------------------------
// STEP2: asm step, trimmed tail (swap32 outputs cover {own,partner}; max of
// the two == global max regardless of orientation -> bit-identical).
// ---------------------------------------------------------------------------
#define STEP2_ASM(avar, evar)                                                       \
    do {                                                                            \
        float x_, b_, q0_, q1_, q2_, q3_, q4_, q5_, q6_, q7_,                       \
              q8_, q9_, q10_, q11_, q12_, q13_, q14_, q15_;                         \
        asm volatile(                                                               \
            "v_mov_b32 %[x], %[aa]\n\t"                                             \
            "s_nop 1\n\t"                                                           \
            "v_permlane16_swap_b32 %[x], %[aa]\n\t"                                 \
            "s_nop 0\n\t"                                                           \
            "v_cndmask_b32 %[bb], %[aa], %[x], %[m16]\n\t"                          \
            "s_nop 1\n\t"                                                           \
            "v_add_f32 %[q0], %[bb], %[t0]\n\t"                                     \
            "v_add_f32_dpp %[q1], %[bb], %[t1] row_ror:1 row_mask:0xf bank_mask:0xf\n\t"  \
            "v_add_f32_dpp %[q2], %[bb], %[t2] row_ror:2 row_mask:0xf bank_mask:0xf\n\t"  \
            "v_add_f32_dpp %[q3], %[bb], %[t3] row_ror:3 row_mask:0xf bank_mask:0xf\n\t"  \
            "v_add_f32_dpp %[q4], %[bb], %[t4] row_ror:4 row_mask:0xf bank_mask:0xf\n\t"  \
            "v_add_f32_dpp %[q5], %[bb], %[t5] row_ror:5 row_mask:0xf bank_mask:0xf\n\t"  \
            "v_add_f32_dpp %[q6], %[bb], %[t6] row_ror:6 row_mask:0xf bank_mask:0xf\n\t"  \
            "v_add_f32_dpp %[q7], %[bb], %[t7] row_ror:7 row_mask:0xf bank_mask:0xf\n\t"  \
            "v_add_f32_dpp %[q8], %[bb], %[t8] row_ror:8 row_mask:0xf bank_mask:0xf\n\t"  \
            "v_add_f32_dpp %[q9], %[bb], %[t9] row_ror:9 row_mask:0xf bank_mask:0xf\n\t"  \
            "v_add_f32_dpp %[q10], %[bb], %[t10] row_ror:10 row_mask:0xf bank_mask:0xf\n\t" \
            "v_add_f32_dpp %[q11], %[bb], %[t11] row_ror:11 row_mask:0xf bank_mask:0xf\n\t" \
            "v_add_f32_dpp %[q12], %[bb], %[t12] row_ror:12 row_mask:0xf bank_mask:0xf\n\t" \
            "v_add_f32_dpp %[q13], %[bb], %[t13] row_ror:13 row_mask:0xf bank_mask:0xf\n\t" \
            "v_add_f32_dpp %[q14], %[bb], %[t14] row_ror:14 row_mask:0xf bank_mask:0xf\n\t" \
            "v_add_f32_dpp %[q15], %[bb], %[t15] row_ror:15 row_mask:0xf bank_mask:0xf\n\t" \
            "v_max3_f32 %[q0], %[q0], %[q1], %[q2]\n\t"                             \
            "v_max3_f32 %[q3], %[q3], %[q4], %[q5]\n\t"                             \
            "v_max3_f32 %[q6], %[q6], %[q7], %[q8]\n\t"                             \
            "v_max3_f32 %[q9], %[q9], %[q10], %[q11]\n\t"                           \
            "v_max3_f32 %[q12], %[q12], %[q13], %[q14]\n\t"                         \
            "v_max3_f32 %[q0], %[q0], %[q3], %[q6]\n\t"                             \
            "v_max3_f32 %[q9], %[q9], %[q12], %[q15]\n\t"                           \
            "v_max_f32 %[q0], %[q0], %[q9]\n\t"                                     \
            "v_mov_b32 %[x], %[q0]\n\t"                                             \
            "s_nop 1\n\t"                                                           \
            "v_permlane32_swap_b32 %[x], %[q0]\n\t"                                 \
            "s_nop 0\n\t"                                                           \
            "v_max_f32 %[q0], %[q0], %[x]\n\t"                                      \
            "v_add_f32 %[aa], %[q0], %[ee]\n\t"                                     \
            : [aa] "+v"(avar), [x] "=&v"(x_), [bb] "=&v"(b_),                       \
              [q0] "=&v"(q0_), [q1] "=&v"(q1_), [q2] "=&v"(q2_), [q3] "=&v"(q3_),   \
              [q4] "=&v"(q4_), [q5] "=&v"(q5_), [q6] "=&v"(q6_), [q7] "=&v"(q7_),   \
              [q8] "=&v"(q8_), [q9] "=&v"(q9_), [q10] "=&v"(q10_),                  \
              [q11] "=&v"(q11_), [q12] "=&v"(q12_), [q13] "=&v"(q13_),              \
              [q14] "=&v"(q14_), [q15] "=&v"(q15_)                                  \
            : [ee] "v"(evar), [t0] "v"(Ti[0]), [t1] "v"(Ti[1]), [t2] "v"(Ti[2]),    \
              [t3] "v"(Ti[3]), [t4] "v"(Ti[4]), [t5] "v"(Ti[5]), [t6] "v"(Ti[6]),   \
              [t7] "v"(Ti[7]), [t8] "v"(Ti[8]), [t9] "v"(Ti[9]), [t10] "v"(Ti[10]), \
              [t11] "v"(Ti[11]), [t12] "v"(Ti[12]), [t13] "v"(Ti[13]),              \
              [t14] "v"(Ti[14]), [t15] "v"(Ti[15]),                                 \
              [m16] "s"(mask16));                                                   \
    } while (0)

// ---------------------------------------------------------------------------
// Kernel 2: forward alpha chain — r9 standalone (64 blocks x 1 wave), STEP2.
// e via 8-deep global register queue; alpha stored in-place over em.
// ---------------------------------------------------------------------------
__global__ __launch_bounds__(64, 1) void viterbi_fwd4(float* __restrict__ em,
                                                      const float* __restrict__ T,
                                                      const float* __restrict__ startT,
                                                      const float* __restrict__ endT,
                                                      float* __restrict__ out) {
    const int l = threadIdx.x;
    const int b = blockIdx.x;
    const int j = l & 31;
    const int h = l >> 5;

    int p0, p1;
    plswap16(j, p0, p1);
    const bool c16 = (((p0 >> 4) & 1) == h);
    const int pm = c16 ? p0 : p1;
    int mk[16];
    ROTALL(mk, pm);

    const unsigned long long mask16 = __ballot(c16);

    float Ti[16];
#pragma unroll
    for (int k = 0; k < 16; ++k) Ti[k] = T[mk[k] * CC + j];

    float* eb = em + (long)b * SS * CC;

    float eq[8];
#pragma unroll
    for (int v = 0; v < 8; ++v) eq[v] = eb[v * 32 + j];

    float a = startT[j] + eq[0];           // alpha_0
    eb[j] = a;
    eq[0] = eb[8 * 32 + j];

    int t = 1;
    for (int g = 0; g < 254; ++g) {
#pragma unroll
        for (int u = 0; u < 8; ++u) {
            STEP2_ASM(a, eq[t & 7]);
            eb[t * 32 + j] = a;
            eq[t & 7] = eb[(t + 8) * 32 + j];
            ++t;
        }
    }
#pragma unroll
    for (int u = 0; u < 7; ++u) {
        STEP2_ASM(a, eq[t & 7]);
        eb[t * 32 + j] = a;
        eq[t & 7] = eb[(t + 8) * 32 + j];
        ++t;
    }
#pragma unroll
    for (int u = 0; u < 8; ++u) {
        STEP2_ASM(a, eq[t & 7]);
        eb[t * 32 + j] = a;
        ++t;
    }

    float v = a + endT[j];
    int idx = j;
#pragma unroll
    for (int d = 1; d <= 16; d <<= 1) {
        float ovv = __shfl_xor(v, d);
        int   oii = __shfl_xor(idx, d);
        bool c = (ovv > v) || (ovv == v && oii < idx);
        v = c ? ovv : v;
        idx = c ? oii : idx;
    }
    if (l == 0) {
        out[b] = v;
        out[BB + (long)b * SS + (SS - 1)] = (float)idx;
    }
}

// ---------------------------------------------------------------------------
// Kernel 3: bp_compose — CH=64 chunks x 32 steps (exact r6 argmax semantics).
// 4096 waves, 4/SIMD. Stores bp (8 dwords/chunk) + chunk LUT G.
// ---------------------------------------------------------------------------
__global__ __launch_bounds__(64, 4) void bp_compose(const float* __restrict__ alpha,
                                                    const float* __restrict__ T,
                                                    unsigned* __restrict__ bp,
                                                    unsigned char* __restrict__ G) {
    const int l = threadIdx.x;
    const int j = l & 31;
    const int h = l >> 5;
    const int b = blockIdx.x >> 6;
    const int k = blockIdx.x & 63;

    int p0, p1;
    plswap16(j, p0, p1);
    const bool c16 = (((p0 >> 4) & 1) == h);
    const int pm = c16 ? p0 : p1;
    int mk[16];
    ROTALL(mk, pm);
    int q0p, q1p;
    plswap32(l, q0p, q1p);
    const bool pick0 = (q0p == (l ^ 32));

    float Ti[16];
    unsigned Bk[16];
#pragma unroll
    for (int kk = 0; kk < 16; ++kk) {
        Ti[kk] = T[mk[kk] * CC + j];
        Bk[kk] = 1u << mk[kk];
    }

    const float* A = alpha + (long)b * SS * CC;
    const int u0 = k << 5;                 // first bp index of this chunk

    float aq[8];
#pragma unroll
    for (int v = 0; v < 8; ++v) aq[v] = A[(u0 + v) * CC + j];

    unsigned sr[8];
#pragma unroll
    for (int p = 0; p < 8; ++p) sr[p] = 0u;

#pragma unroll
    for (int g8 = 0; g8 < 4; ++g8) {
#pragma unroll
        for (int v = 0; v < 8; ++v) {
            const int u = g8 * 8 + v;
            float av = aq[v];
            if (g8 < 3) aq[v] = A[(u0 + (g8 + 1) * 8 + v) * CC + j];

            int x, y;
            plswap16(__float_as_int(av), x, y);
            int base = c16 ? x : y;
            int rot[16];
            ROTALL(rot, base);
            float s[16];
#pragma unroll
            for (int kk = 0; kk < 16; ++kk) s[kk] = __int_as_float(rot[kk]) + Ti[kk];

            float m0 = fmax3_(s[0], s[1], s[2]);
            float m1 = fmax3_(s[3], s[4], s[5]);
            float m2 = fmax3_(s[6], s[7], s[8]);
            float m3 = fmax3_(s[9], s[10], s[11]);
            float m4 = fmax3_(s[12], s[13], s[14]);
            float mv = fmaxf(fmax3_(m0, m1, m2), fmax3_(m3, m4, s[15]));

            int xm, ym;
            plswap32(__float_as_int(mv), xm, ym);
            float ov = __int_as_float(pick0 ? xm : ym);
            float gv = fmaxf(mv, ov);

            unsigned c0 = (s[0] == gv) ? Bk[0] : 0u,   c1 = (s[1] == gv) ? Bk[1] : 0u;
            unsigned c2 = (s[2] == gv) ? Bk[2] : 0u,   c3 = (s[3] == gv) ? Bk[3] : 0u;
            unsigned c4 = (s[4] == gv) ? Bk[4] : 0u,   c5 = (s[5] == gv) ? Bk[5] : 0u;
            unsigned c6 = (s[6] == gv) ? Bk[6] : 0u,   c7 = (s[7] == gv) ? Bk[7] : 0u;
            unsigned c8 = (s[8] == gv) ? Bk[8] : 0u,   c9 = (s[9] == gv) ? Bk[9] : 0u;
            unsigned c10 = (s[10] == gv) ? Bk[10] : 0u, c11 = (s[11] == gv) ? Bk[11] : 0u;
            unsigned c12 = (s[12] == gv) ? Bk[12] : 0u, c13 = (s[13] == gv) ? Bk[13] : 0u;
            unsigned c14 = (s[14] == gv) ? Bk[14] : 0u, c15 = (s[15] == gv) ? Bk[15] : 0u;
            unsigned msk = ((c0 | c1 | c2) | (c3 | c4 | c5)) |
                           ((c6 | c7 | c8) | (c9 | c10 | c11)) |
                           ((c12 | c13 | c14) | c15);

            int xk, yk;
            plswap32((int)msk, xk, yk);
            unsigned om = (unsigned)(pick0 ? xk : yk);
            int wi = __builtin_ctz(msk | om);

            if (u == 31 && k == CH - 1) wi = j;   // bp slot 2047 = identity
            sr[u >> 2] |= (unsigned)wi << ((u & 3) * 8);
        }
    }

#pragma unroll
    for (int p = 0; p < 8; ++p)
        bp[((unsigned)(8 * k + p) * BB + b) * CC + j] = sr[p];

    int g = j;
#pragma unroll
    for (int rel = 31; rel >= 0; --rel) {
        unsigned dw = (unsigned)__builtin_amdgcn_ds_bpermute((g | (l & 32)) << 2,
                                                             (int)sr[rel >> 2]);
        g = (int)((dw >> ((rel & 3) * 8)) & 31u);
    }
    G[(b * CH + k) * 32 + j] = (unsigned char)g;
}

// ---------------------------------------------------------------------------
// Kernel 4: bt_scan — 2 blocks x 32 batches; stage G (64 KB/block) in LDS,
// walk 64 chunk LUTs per batch, emit boundary tags.
// ---------------------------------------------------------------------------
__global__ __launch_bounds__(64) void bt_scan(const unsigned char* __restrict__ G,
                                              const float* __restrict__ out,
                                              int* __restrict__ tagB) {
    __shared__ unsigned char Gs[32 * CH * 32];     // 64 KB
    const int l = threadIdx.x;
    const int bbase = blockIdx.x * 32;
    const float4* Gg = (const float4*)(G + (size_t)bbase * CH * 32);
    float4* Gls = (float4*)Gs;
#pragma unroll
    for (int i = 0; i < 64; ++i) Gls[l + i * 64] = Gg[l + i * 64];
    __syncthreads();

    if (l < 32) {
        const int b = bbase + l;
        int cur = (int)out[BB + (long)b * SS + (SS - 1)];
        for (int k = CH - 1; k >= 0; --k) {
            cur = Gs[(l * CH + k) * 32 + cur];
            tagB[b * CH + k] = cur;                // = tag at t = 32k
        }
    }
}

// ---------------------------------------------------------------------------
// Kernel 5: bt_emit — 4096 blocks, each re-walks its 32-step chunk.
// ---------------------------------------------------------------------------
__global__ __launch_bounds__(64, 4) void bt_emit(const unsigned* __restrict__ bp,
                                                 const int* __restrict__ tagB,
                                                 const float* __restrict__ outR,
                                                 float* __restrict__ out) {
    const int l = threadIdx.x;
    const int b = blockIdx.x >> 6;
    const int k = blockIdx.x & 63;

    unsigned sr[8];
#pragma unroll
    for (int p = 0; p < 8; ++p) sr[p] = bp[((unsigned)(8 * k + p) * BB + b) * CC + (l & 31)];

    int start = (k == CH - 1) ? (int)outR[BB + (long)b * SS + (SS - 1)]
                              : tagB[b * CH + k + 1];
    int g = start, cap = start;
#pragma unroll
    for (int rel = 31; rel >= 0; --rel) {
        unsigned dw = (unsigned)__builtin_amdgcn_ds_bpermute((g | (l & 32)) << 2,
                                                             (int)sr[rel >> 2]);
        g = (int)((dw >> ((rel & 3) * 8)) & 31u);
        cap = (l == rel) ? g : cap;
    }
    if (l < 32) out[BB + (long)b * SS + k * 32 + l] = (float)cap;
}

// ---------------------------------------------------------------------------
extern "C" void kernel_launch(void* const* d_in, const int* in_sizes, int n_in,
                              void* d_out, int out_size, void* d_ws, size_t ws_size,
                              hipStream_t stream) {
    const float* X      = (const float*)d_in[0];
    const float* W      = (const float*)d_in[1];
    const float* bias   = (const float*)d_in[2];
    const float* T      = (const float*)d_in[3];
    const float* startT = (const float*)d_in[4];
    const float* endT   = (const float*)d_in[5];
    float* out = (float*)d_out;

    float*    em = (float*)d_ws;                                        // 16 MB (e -> alpha in-place)
    unsigned* bp = (unsigned*)((char*)d_ws + (size_t)BB * SS * CC * 4); // 4 MB @ 16 MB
    unsigned char* G    = (unsigned char*)d_ws + (20u << 20);           // 128 KB @ 20 MB
    int*           tagB = (int*)((char*)d_ws + (20u << 20) + 131072);   // 16 KB

    emis_kernel<<<(BB * SS) / 64, 256, 0, stream>>>(X, W, bias, em);
    viterbi_fwd4<<<BB, 64, 0, stream>>>(em, T, startT, endT, out);
    bp_compose<<<BB * CH, 64, 0, stream>>>(em, T, bp, G);
    bt_scan<<<2, 64, 0, stream>>>(G, out, tagB);
    bt_emit<<<BB * CH, 64, 0, stream>>>(bp, tagB, out, out);
}